// Round 5
// baseline (7124.961 us; speedup 1.0000x reference)
//
#include <hip/hip_runtime.h>
#include <stdint.h>
#include <stddef.h>

// Problem dims
#define B_ 1024
#define S_ 128
#define D_ 256
#define H_ 2048
#define O_ 10
#define V_ 10

typedef unsigned short u16;
typedef short v8s __attribute__((ext_vector_type(8)));    // 8 x bf16 (4 VGPRs) MFMA A/B frag
typedef float v4f __attribute__((ext_vector_type(4)));    // 4 x f32 MFMA C/D frag
typedef u16 u16x4 __attribute__((ext_vector_type(4)));

__device__ __forceinline__ u16 f2bf(float f) {
  unsigned int u = __float_as_uint(f);
  u += 0x7FFFu + ((u >> 16) & 1u);   // RNE
  return (u16)(u >> 16);
}
__device__ __forceinline__ float bf2f(u16 h) {
  return __uint_as_float(((unsigned int)h) << 16);
}
__device__ __forceinline__ float fast_tanh(float x) {
  float e = __expf(2.0f * x);
  return 1.0f - 2.0f / (e + 1.0f);
}
__device__ __forceinline__ void gl2lds16(const void* g, void* l) {
  __builtin_amdgcn_global_load_lds(
      (const __attribute__((address_space(1))) uint32_t*)g,
      (__attribute__((address_space(3))) uint32_t*)l, 16, 0, 0);
}

// ---------------- zero the barrier state (ws is re-poisoned before every call) -----
__global__ void zero_sync(int* __restrict__ sync) {
  sync[threadIdx.x] = 0;   // 512 ints
}

// ---------------- Txh[v][h] = b_hx[h] + sum_d embed[v][d]*W_hx[h][d] ----------------
__global__ __launch_bounds__(256) void make_table(const float* __restrict__ embed,
                                                  const float* __restrict__ W_hx,
                                                  const float* __restrict__ b_hx,
                                                  float* __restrict__ Txh) {
  int idx = blockIdx.x * 256 + threadIdx.x;   // 10*2048 = 20480
  int v = idx >> 11, h = idx & 2047;
  const float4* e4 = (const float4*)(embed + v * D_);
  const float4* w4 = (const float4*)(W_hx + (size_t)h * D_);
  float s = b_hx[h];
#pragma unroll 4
  for (int d = 0; d < D_ / 4; ++d) {
    float4 a = e4[d], b = w4[d];
    s = fmaf(a.x, b.x, s); s = fmaf(a.y, b.y, s);
    s = fmaf(a.z, b.z, s); s = fmaf(a.w, b.w, s);
  }
  Txh[idx] = s;
}

// ---------------- W_hh (f32) -> bf16, same [N][K] layout ----------------
__global__ __launch_bounds__(256) void conv_w(const float* __restrict__ W,
                                              u16* __restrict__ Wb) {
  int i = blockIdx.x * 256 + threadIdx.x;     // over 4M/4 = 1M float4
  float4 w = ((const float4*)W)[i];
  u16x4 o = { f2bf(w.x), f2bf(w.y), f2bf(w.z), f2bf(w.w) };
  ((u16x4*)Wb)[i] = o;
}

// ---------------- h0[b][j] = tanh(Txh[x[b,0]][j])  (no b_hh at step 0) ----------------
__global__ __launch_bounds__(256) void init_h0(const float* __restrict__ Txh,
                                               const int* __restrict__ x,
                                               u16* __restrict__ H0) {
  int idx = blockIdx.x * 256 + threadIdx.x;   // 1024*2048 = 2M
  int b = idx >> 11, j = idx & 2047;
  int xv = x[b * S_];
  H0[idx] = f2bf(fast_tanh(Txh[xv * H_ + j]));
}

// ---------------- persistent weight-stationary RNN ----------------
// 256 WGs x 512 threads, 1 WG/CU (forced by 128 KB LDS -> all co-resident).
// Partition: mg = (bid>>1)&3 (m-range 256 rows, XCD-pair-local);
//            ng = (bid>>3)*2 + (bid&1) (n-range 32 cols).
// W block [32 n x 2048 k] bf16 lives in LDS for all 127 steps; per step each CU
// streams A = h[m-range] (1 MB) from L2/L3, MFMAs, fused epilogue, device barrier.
// LDS W layout: row n (0..31) x 256 chunks of 8 bf16; chunk swizzle cs = c ^ (n&15)
// -> frag reads are 2-way-per-phase max (free, m136).
// Barrier: monotonic epochs, 2-level tree (8 strided group counters -> global ->
// epoch), one thread/WG; fences system-scope (L2 wb/inv covers cross-XCD h).
__global__ __launch_bounds__(512, 2) void rnn_persist(u16* __restrict__ Ha,
                                                      u16* __restrict__ Hb,
                                                      const u16* __restrict__ Wb,
                                                      const float* __restrict__ Txh,
                                                      const int* __restrict__ x,
                                                      const float* __restrict__ b_hh,
                                                      int* sync) {
  __shared__ __align__(16) u16 Wlds[32 * 2048];   // 128 KB

  const int tid = threadIdx.x;
  const int bid = blockIdx.x;
  const int mg = (bid >> 1) & 3;
  const int ng = ((bid >> 3) << 1) | (bid & 1);
  const int mbase = mg * 256;
  const int nbase = ng * 32;

  const int w = tid >> 6, l = tid & 63;
  const int lane16 = l & 15, quad = l >> 4;

  // ---- load W block into LDS (once) ----
#pragma unroll
  for (int it = 0; it < 16; ++it) {
    int s = it * 512 + tid;                     // 8192 slots of 16 B
    int n = s >> 8, cs = s & 255;
    int c = cs ^ (n & 15);                      // global chunk (XOR self-inverse)
    const u16* g = Wb + (size_t)(nbase + n) * H_ + c * 8;
    u16* lp = Wlds + (size_t)(it * 512 + (w << 6)) * 8;  // wave-uniform; lane at +l*16B
    gl2lds16(g, lp);
  }
  __syncthreads();

  const int mstrip = mbase + w * 32;            // this wave's 32 m-rows

  for (int t = 1; t < S_; ++t) {
    const u16* Hin = (t & 1) ? Ha : Hb;
    u16* Hout = (t & 1) ? Hb : Ha;

    v4f acc[2][2];
#pragma unroll
    for (int i = 0; i < 2; ++i)
#pragma unroll
      for (int j = 0; j < 2; ++j) acc[i][j] = (v4f){0.f, 0.f, 0.f, 0.f};

    // A-frag row pointers (element offset quad*8 baked in)
    const u16* ar0 = Hin + (size_t)(mstrip + lane16) * H_ + quad * 8;
    const u16* ar1 = Hin + (size_t)(mstrip + 16 + lane16) * H_ + quad * 8;

    // register double-buffered A prefetch, groups of 4 k-chunks (k-chunk = 32)
    v8s abuf[2][2][4];
#pragma unroll
    for (int c = 0; c < 4; ++c) {
      abuf[0][0][c] = *(const v8s*)(ar0 + c * 32);
      abuf[0][1][c] = *(const v8s*)(ar1 + c * 32);
    }

#pragma unroll 4
    for (int g = 0; g < 16; ++g) {
      const int par = g & 1, nxt = par ^ 1;
      if (g < 15) {
#pragma unroll
        for (int c = 0; c < 4; ++c) {
          int off = ((g + 1) * 4 + c) * 32;
          abuf[nxt][0][c] = *(const v8s*)(ar0 + off);
          abuf[nxt][1][c] = *(const v8s*)(ar1 + off);
        }
      }
#pragma unroll
      for (int c = 0; c < 4; ++c) {
        int c8 = (g * 4 + c) * 4 + quad;        // chunk-of-8 index (0..255)
        v8s bf[2];
#pragma unroll
        for (int j = 0; j < 2; ++j) {
          int n = j * 16 + lane16;
          int cs = c8 ^ (n & 15);
          bf[j] = *(const v8s*)&Wlds[((size_t)n * 256 + cs) * 8];
        }
#pragma unroll
        for (int i = 0; i < 2; ++i)
#pragma unroll
          for (int j = 0; j < 2; ++j)
            acc[i][j] = __builtin_amdgcn_mfma_f32_16x16x32_bf16(abuf[par][i][c], bf[j],
                                                                acc[i][j], 0, 0, 0);
      }
    }

    // ---- fused epilogue: C/D layout col=lane&15, row=quad*4+reg [m89-verified] ----
    const int colb = nbase + lane16;
    float bh[2];
#pragma unroll
    for (int j = 0; j < 2; ++j) bh[j] = b_hh[colb + j * 16];
#pragma unroll
    for (int i = 0; i < 2; ++i) {
#pragma unroll
      for (int r = 0; r < 4; ++r) {
        int row = mstrip + i * 16 + quad * 4 + r;
        const float* trow = Txh + x[row * S_ + t] * H_;
        u16* orow = Hout + (size_t)row * H_;
#pragma unroll
        for (int j = 0; j < 2; ++j) {
          int col = colb + j * 16;
          float v = acc[i][j][r] + trow[col] + bh[j];
          orow[col] = f2bf(fast_tanh(v));
        }
      }
    }

    // ---- device barrier (monotonic epoch, 2-level tree) ----
    __syncthreads();                            // all waves' stores issued (vmcnt drained)
    if (tid == 0) {
      __builtin_amdgcn_fence(__ATOMIC_RELEASE, "");   // system: L2 writeback
      int a = __hip_atomic_fetch_add(&sync[(bid & 7) * 32], 1,
                                     __ATOMIC_RELAXED, __HIP_MEMORY_SCOPE_AGENT);
      if (a == t * 32 - 1) {                    // last of my 32-WG group this step
        int b = __hip_atomic_fetch_add(&sync[256], 1,
                                       __ATOMIC_RELAXED, __HIP_MEMORY_SCOPE_AGENT);
        if (b == t * 8 - 1)                     // global last
          __hip_atomic_store(&sync[288], t, __ATOMIC_RELEASE, __HIP_MEMORY_SCOPE_AGENT);
      }
      int spin = 0;
      while (__hip_atomic_load(&sync[288], __ATOMIC_RELAXED,
                               __HIP_MEMORY_SCOPE_AGENT) < t) {
        __builtin_amdgcn_s_sleep(8);
        if (++spin > (1 << 22)) break;          // deadlock -> wrong-answer, never hang
      }
    }
    __syncthreads();
    __builtin_amdgcn_fence(__ATOMIC_ACQUIRE, "");     // system: L1/L2 invalidate
  }
}

// ---------------- o = hT @ W_oh^T + b_oh ; softmax over 10 ----------------
__global__ __launch_bounds__(256) void out_softmax(const u16* __restrict__ Hf,
                                                   const float* __restrict__ W_oh,
                                                   const float* __restrict__ b_oh,
                                                   float* __restrict__ out) {
  int b = blockIdx.x, tid = threadIdx.x;
  float hv[8];
  const u16* hr = Hf + (size_t)b * H_ + tid * 8;
#pragma unroll
  for (int u = 0; u < 8; ++u) hv[u] = bf2f(hr[u]);
  float acc[O_];
#pragma unroll
  for (int i = 0; i < O_; ++i) {
    const float* wr = W_oh + (size_t)i * H_ + tid * 8;
    float s = 0.f;
#pragma unroll
    for (int u = 0; u < 8; ++u) s = fmaf(hv[u], wr[u], s);
    acc[i] = s;
  }
#pragma unroll
  for (int off = 32; off > 0; off >>= 1)
#pragma unroll
    for (int i = 0; i < O_; ++i) acc[i] += __shfl_down(acc[i], off);
  __shared__ float red[4][O_];
  if ((tid & 63) == 0)
#pragma unroll
    for (int i = 0; i < O_; ++i) red[tid >> 6][i] = acc[i];
  __syncthreads();
  if (tid == 0) {
    float o[O_], mx = -1e30f;
#pragma unroll
    for (int i = 0; i < O_; ++i) {
      o[i] = red[0][i] + red[1][i] + red[2][i] + red[3][i] + b_oh[i];
      mx = fmaxf(mx, o[i]);
    }
    float se = 0.f;
#pragma unroll
    for (int i = 0; i < O_; ++i) { o[i] = __expf(o[i] - mx); se += o[i]; }
    float inv = 1.f / se;
#pragma unroll
    for (int i = 0; i < O_; ++i) out[b * O_ + i] = o[i] * inv;
  }
}

extern "C" void kernel_launch(void* const* d_in, const int* in_sizes, int n_in,
                              void* d_out, int out_size, void* d_ws, size_t ws_size,
                              hipStream_t stream) {
  const int*   x     = (const int*)  d_in[0];
  const float* embed = (const float*)d_in[1];
  const float* W_hx  = (const float*)d_in[2];
  const float* b_hx  = (const float*)d_in[3];
  const float* W_hh  = (const float*)d_in[4];
  const float* b_hh  = (const float*)d_in[5];
  const float* W_oh  = (const float*)d_in[6];
  const float* b_oh  = (const float*)d_in[7];
  float* out = (float*)d_out;

  // workspace: Txh 80KB | Wb 8MB | Ha 4MB | Hb 4MB | sync 2KB  (~16.1 MB)
  char* ws = (char*)d_ws;
  float* Txh = (float*)ws;
  u16* Wb    = (u16*)(ws + (80 << 10));
  u16* Ha    = (u16*)(ws + (80 << 10) + (8 << 20));
  u16* Hb    = (u16*)(ws + (80 << 10) + (12 << 20));
  int* syncp = (int*)(ws + (80 << 10) + (16 << 20));

  zero_sync<<<1, 512, 0, stream>>>(syncp);
  make_table<<<80, 256, 0, stream>>>(embed, W_hx, b_hx, Txh);
  conv_w<<<4096, 256, 0, stream>>>(W_hh, Wb);
  init_h0<<<8192, 256, 0, stream>>>(Txh, x, Ha);

  rnn_persist<<<256, 512, 0, stream>>>(Ha, Hb, Wb, Txh, x, b_hh, syncp);

  // t=127 (odd) wrote Hb
  out_softmax<<<B_, 256, 0, stream>>>(Hb, W_oh, b_oh, out);
}

// Round 6
// 5072.832 us; speedup vs baseline: 1.4045x; 1.4045x over previous
//
#include <hip/hip_runtime.h>
#include <stdint.h>
#include <stddef.h>

// Problem dims
#define B_ 1024
#define S_ 128
#define D_ 256
#define H_ 2048
#define O_ 10
#define V_ 10

typedef unsigned short u16;
typedef short v8s __attribute__((ext_vector_type(8)));    // 8 x bf16 (4 VGPRs) MFMA A/B frag
typedef float v4f __attribute__((ext_vector_type(4)));    // 4 x f32 MFMA C/D frag
typedef u16 u16x4 __attribute__((ext_vector_type(4)));

__device__ __forceinline__ u16 f2bf(float f) {
  unsigned int u = __float_as_uint(f);
  u += 0x7FFFu + ((u >> 16) & 1u);   // RNE
  return (u16)(u >> 16);
}
__device__ __forceinline__ float bf2f(u16 h) {
  return __uint_as_float(((unsigned int)h) << 16);
}
__device__ __forceinline__ float fast_tanh(float x) {
  float e = __expf(2.0f * x);
  return 1.0f - 2.0f / (e + 1.0f);
}
__device__ __forceinline__ void gl2lds16(const void* g, void* l) {
  __builtin_amdgcn_global_load_lds(
      (const __attribute__((address_space(1))) uint32_t*)g,
      (__attribute__((address_space(3))) uint32_t*)l, 16, 0, 0);
}

// ---------------- Txh[v][h] = b_hx[h] + sum_d embed[v][d]*W_hx[h][d] ----------------
__global__ __launch_bounds__(256) void make_table(const float* __restrict__ embed,
                                                  const float* __restrict__ W_hx,
                                                  const float* __restrict__ b_hx,
                                                  float* __restrict__ Txh) {
  int idx = blockIdx.x * 256 + threadIdx.x;   // 10*2048 = 20480
  int v = idx >> 11, h = idx & 2047;
  const float4* e4 = (const float4*)(embed + v * D_);
  const float4* w4 = (const float4*)(W_hx + (size_t)h * D_);
  float s = b_hx[h];
#pragma unroll 4
  for (int d = 0; d < D_ / 4; ++d) {
    float4 a = e4[d], b = w4[d];
    s = fmaf(a.x, b.x, s); s = fmaf(a.y, b.y, s);
    s = fmaf(a.z, b.z, s); s = fmaf(a.w, b.w, s);
  }
  Txh[idx] = s;
}

// ---------------- W_hh (f32, [n][k] row-major) -> frag-major bf16 Wt ----------------
// Wt layout: [ng 0..31][kt 0..3][frag 0..63][lane 0..63][j 0..7] u16.
// frag = kti*4 + nb  (kti 0..15: k-iter of 32 within the 512-k tile; nb 0..3: n-block
// of 16 within the 64-col group). Lane l holds W[n = ng*64 + nb*16 + (l&15)]
// [k = kt*512 + kti*32 + (l>>4)*8 + j] — exactly the verified B-frag read pattern,
// so LDS staging is a LINEAR 64 KB copy and frag reads are contiguous ds_read_b128.
__global__ __launch_bounds__(256) void conv_w(const float* __restrict__ W,
                                              u16* __restrict__ Wt) {
  int idx = blockIdx.x * 256 + threadIdx.x;   // 512K threads, 16 B each
  int l = idx & 63;
  int frag = (idx >> 6) & 63;
  int kt = (idx >> 12) & 3;
  int ng = idx >> 14;
  int nb = frag & 3, kti = frag >> 2;
  int n = ng * 64 + nb * 16 + (l & 15);
  int k = kt * 512 + kti * 32 + (l >> 4) * 8;
  const float* src = W + (size_t)n * H_ + k;
  float4 w0 = ((const float4*)src)[0];
  float4 w1 = ((const float4*)src)[1];
  u16x4 o0 = { f2bf(w0.x), f2bf(w0.y), f2bf(w0.z), f2bf(w0.w) };
  u16x4 o1 = { f2bf(w1.x), f2bf(w1.y), f2bf(w1.z), f2bf(w1.w) };
  ((u16x4*)(Wt + (size_t)idx * 8))[0] = o0;
  ((u16x4*)(Wt + (size_t)idx * 8))[1] = o1;
}

// ---------------- h0[b][j] = tanh(Txh[x[b,0]][j])  (no b_hh at step 0) ----------------
__global__ __launch_bounds__(256) void init_h0(const float* __restrict__ Txh,
                                               const int* __restrict__ x,
                                               u16* __restrict__ H0) {
  int idx = blockIdx.x * 256 + threadIdx.x;   // 1024*2048 = 2M
  int b = idx >> 11, j = idx & 2047;
  int xv = x[b * S_];
  H0[idx] = f2bf(fast_tanh(Txh[xv * H_ + j]));
}

// ---------------- one recurrence step ----------------
// C[1024 x 2048] = Hin * W^T. Grid 256 (1 WG/CU), 256 threads (4 waves).
// WG tile 128m x 64n; waves 2m x 2n, wave tile 64m x 32n:
//   per k-iter(32): 4 A-frags (global->VGPR, no LDS), 2 W-frags (LDS, each feeds
//   4 MFMAs -> 53 B/cyc LDS demand), 8 MFMAs. BK=512, double-buffered (128 KB LDS),
//   only 4 barrier drains per step. 1-deep register prefetch on A and W-frags.
// XCD swizzle: per-XCD footprint A 2 MB + W 2 MB = L2-resident.
__global__ __launch_bounds__(256) void rnn_step(const u16* __restrict__ Hin,
                                                const u16* __restrict__ Wt,
                                                const float* __restrict__ Txh,
                                                const int* __restrict__ x,
                                                const float* __restrict__ b_hh,
                                                u16* __restrict__ Hout,
                                                int t) {
  __shared__ __align__(16) u16 Ws[2][32768];   // 2 x 64 KB

  const int tid = threadIdx.x;
  const int bid = blockIdx.x;
  const int xcd = bid & 7, sl = bid >> 3;
  const int mg = (xcd >> 2) * 4 + (sl >> 3);   // 0..7  (128-row groups)
  const int ng = (xcd & 3) * 8 + (sl & 7);     // 0..31 (64-col groups)
  const int bm = mg * 128;

  const int w = tid >> 6, l = tid & 63;
  const int wm = w >> 1, wn = w & 1;           // wave = 64m x 32n at (wm*64, wn*32)
  const int lane16 = l & 15, quad = l >> 4;

  const u16* wsrc = Wt + (size_t)ng * 4 * 32768;   // + kt*32768

  v4f acc[4][2];
#pragma unroll
  for (int i = 0; i < 4; ++i)
#pragma unroll
    for (int j = 0; j < 2; ++j) acc[i][j] = (v4f){0.f, 0.f, 0.f, 0.f};

  // per-lane A base: row = bm + wm*64 + i*16 + lane16, byte col = k*2 + quad*16
  const u16* abase = Hin + (size_t)(bm + wm * 64 + lane16) * H_ + quad * 8;

  // stage kt into LDS buffer b: linear 64 KB copy, 16 issues of 256 lanes x 16 B
#define STAGE(kt, b)                                                        \
  {                                                                         \
    const u16* g = wsrc + (size_t)(kt) * 32768;                             \
    _Pragma("unroll")                                                       \
    for (int i = 0; i < 16; ++i)                                            \
      gl2lds16(g + (size_t)(i * 256 + tid) * 8,                             \
               &Ws[b][(size_t)(i * 256 + (w << 6)) * 8]);                   \
  }

  STAGE(0, 0);
  // prefetch A for kk=0
  v8s ab[2][4];
#pragma unroll
  for (int i = 0; i < 4; ++i) ab[0][i] = *(const v8s*)(abase + (size_t)i * 16 * H_);
  __syncthreads();

  v8s wf[2][2];
  for (int kt = 0; kt < 4; ++kt) {
    const int cur = kt & 1;
    if (kt < 3) STAGE(kt + 1, cur ^ 1);
    // W-frag prefetch for kti=0 of this buffer
#pragma unroll
    for (int nb = 0; nb < 2; ++nb)
      wf[0][nb] = *(const v8s*)&Ws[cur][(size_t)((0 * 4 + wn * 2 + nb) * 512 + l * 8)];

#pragma unroll
    for (int kti = 0; kti < 16; ++kti) {
      const int kk = kt * 16 + kti;            // global k-iter (k = kk*32)
      const int par = kk & 1;
      // prefetch A for kk+1
      if (kk < 63) {
        const u16* ap = abase + (size_t)(kk + 1) * 32;
#pragma unroll
        for (int i = 0; i < 4; ++i) ab[par ^ 1][i] = *(const v8s*)(ap + (size_t)i * 16 * H_);
      }
      // prefetch W-frags for kti+1 (same buffer)
      if (kti < 15) {
#pragma unroll
        for (int nb = 0; nb < 2; ++nb)
          wf[(kti + 1) & 1][nb] =
              *(const v8s*)&Ws[cur][(size_t)(((kti + 1) * 4 + wn * 2 + nb) * 512 + l * 8)];
      }
#pragma unroll
      for (int i = 0; i < 4; ++i)
#pragma unroll
        for (int nb = 0; nb < 2; ++nb)
          acc[i][nb] = __builtin_amdgcn_mfma_f32_16x16x32_bf16(ab[par][i], wf[kti & 1][nb],
                                                               acc[i][nb], 0, 0, 0);
    }
    __syncthreads();   // stage(kt+1) landed; all waves done with cur before kt+2 reuse
  }

  // epilogue: C/D layout col=lane&15, row=quad*4+reg [m89-verified]
  const int colb = ng * 64 + wn * 32 + lane16;
  float bh[2];
#pragma unroll
  for (int nb = 0; nb < 2; ++nb) bh[nb] = b_hh[colb + nb * 16];
#pragma unroll
  for (int i = 0; i < 4; ++i) {
#pragma unroll
    for (int r = 0; r < 4; ++r) {
      int row = bm + wm * 64 + i * 16 + quad * 4 + r;
      const float* trow = Txh + x[row * S_ + t] * H_;
      u16* orow = Hout + (size_t)row * H_;
#pragma unroll
      for (int nb = 0; nb < 2; ++nb) {
        int col = colb + nb * 16;
        float v = acc[i][nb][r] + trow[col] + bh[nb];
        orow[col] = f2bf(fast_tanh(v));
      }
    }
  }
#undef STAGE
}

// ---------------- o = hT @ W_oh^T + b_oh ; softmax over 10 ----------------
__global__ __launch_bounds__(256) void out_softmax(const u16* __restrict__ Hf,
                                                   const float* __restrict__ W_oh,
                                                   const float* __restrict__ b_oh,
                                                   float* __restrict__ out) {
  int b = blockIdx.x, tid = threadIdx.x;
  float hv[8];
  const u16* hr = Hf + (size_t)b * H_ + tid * 8;
#pragma unroll
  for (int u = 0; u < 8; ++u) hv[u] = bf2f(hr[u]);
  float acc[O_];
#pragma unroll
  for (int i = 0; i < O_; ++i) {
    const float* wr = W_oh + (size_t)i * H_ + tid * 8;
    float s = 0.f;
#pragma unroll
    for (int u = 0; u < 8; ++u) s = fmaf(hv[u], wr[u], s);
    acc[i] = s;
  }
#pragma unroll
  for (int off = 32; off > 0; off >>= 1)
#pragma unroll
    for (int i = 0; i < O_; ++i) acc[i] += __shfl_down(acc[i], off);
  __shared__ float red[4][O_];
  if ((tid & 63) == 0)
#pragma unroll
    for (int i = 0; i < O_; ++i) red[tid >> 6][i] = acc[i];
  __syncthreads();
  if (tid == 0) {
    float o[O_], mx = -1e30f;
#pragma unroll
    for (int i = 0; i < O_; ++i) {
      o[i] = red[0][i] + red[1][i] + red[2][i] + red[3][i] + b_oh[i];
      mx = fmaxf(mx, o[i]);
    }
    float se = 0.f;
#pragma unroll
    for (int i = 0; i < O_; ++i) { o[i] = __expf(o[i] - mx); se += o[i]; }
    float inv = 1.f / se;
#pragma unroll
    for (int i = 0; i < O_; ++i) out[b * O_ + i] = o[i] * inv;
  }
}

extern "C" void kernel_launch(void* const* d_in, const int* in_sizes, int n_in,
                              void* d_out, int out_size, void* d_ws, size_t ws_size,
                              hipStream_t stream) {
  const int*   x     = (const int*)  d_in[0];
  const float* embed = (const float*)d_in[1];
  const float* W_hx  = (const float*)d_in[2];
  const float* b_hx  = (const float*)d_in[3];
  const float* W_hh  = (const float*)d_in[4];
  const float* b_hh  = (const float*)d_in[5];
  const float* W_oh  = (const float*)d_in[6];
  const float* b_oh  = (const float*)d_in[7];
  float* out = (float*)d_out;

  // workspace: Txh 80KB | Wt 8MB | Ha 4MB | Hb 4MB  (~16.1 MB)
  char* ws = (char*)d_ws;
  float* Txh = (float*)ws;
  u16* Wt    = (u16*)(ws + (80 << 10));
  u16* Ha    = (u16*)(ws + (80 << 10) + (8 << 20));
  u16* Hb    = (u16*)(ws + (80 << 10) + (12 << 20));

  make_table<<<80, 256, 0, stream>>>(embed, W_hx, b_hx, Txh);
  conv_w<<<2048, 256, 0, stream>>>(W_hh, Wt);
  init_h0<<<8192, 256, 0, stream>>>(Txh, x, Ha);

  for (int t = 1; t < S_; ++t) {
    const u16* hin = (t & 1) ? Ha : Hb;
    u16* hout = (t & 1) ? Hb : Ha;
    rnn_step<<<256, 256, 0, stream>>>(hin, Wt, Txh, x, b_hh, hout, t);
  }
  // t=127 (odd) wrote Hb
  out_softmax<<<B_, 256, 0, stream>>>(Hb, W_oh, b_oh, out);
}

// Round 7
// 3847.201 us; speedup vs baseline: 1.8520x; 1.3186x over previous
//
#include <hip/hip_runtime.h>
#include <stdint.h>
#include <stddef.h>

// Problem dims
#define B_ 1024
#define S_ 128
#define D_ 256
#define H_ 2048
#define O_ 10
#define V_ 10

typedef unsigned short u16;
typedef short v8s __attribute__((ext_vector_type(8)));    // 8 x bf16 (4 VGPRs) MFMA A/B frag
typedef float v4f __attribute__((ext_vector_type(4)));    // 4 x f32 MFMA C/D frag
typedef u16 u16x4 __attribute__((ext_vector_type(4)));
typedef u16 u16x8 __attribute__((ext_vector_type(8)));

__device__ __forceinline__ u16 f2bf(float f) {
  unsigned int u = __float_as_uint(f);
  u += 0x7FFFu + ((u >> 16) & 1u);   // RNE
  return (u16)(u >> 16);
}
__device__ __forceinline__ float bf2f(u16 h) {
  return __uint_as_float(((unsigned int)h) << 16);
}
__device__ __forceinline__ float fast_tanh(float x) {
  float e = __expf(2.0f * x);
  return 1.0f - 2.0f / (e + 1.0f);
}
__device__ __forceinline__ void gl2lds16(const void* g, void* l) {
  // per-lane GLOBAL address; LDS dst = wave-uniform base + lane*16B
  __builtin_amdgcn_global_load_lds(
      (const __attribute__((address_space(1))) uint32_t*)g,
      (__attribute__((address_space(3))) uint32_t*)l, 16, 0, 0);
}

// ---------------- Txh[v][h] = b_hx[h] + sum_d embed[v][d]*W_hx[h][d] ----------------
__global__ __launch_bounds__(256) void make_table(const float* __restrict__ embed,
                                                  const float* __restrict__ W_hx,
                                                  const float* __restrict__ b_hx,
                                                  float* __restrict__ Txh) {
  int idx = blockIdx.x * 256 + threadIdx.x;   // 10*2048 = 20480
  int v = idx >> 11, h = idx & 2047;
  const float4* e4 = (const float4*)(embed + v * D_);
  const float4* w4 = (const float4*)(W_hx + (size_t)h * D_);
  float s = b_hx[h];
#pragma unroll 4
  for (int d = 0; d < D_ / 4; ++d) {
    float4 a = e4[d], b = w4[d];
    s = fmaf(a.x, b.x, s); s = fmaf(a.y, b.y, s);
    s = fmaf(a.z, b.z, s); s = fmaf(a.w, b.w, s);
  }
  Txh[idx] = s;
}

// ---------------- W_hh (f32) -> bf16, same [N][K] layout ----------------
__global__ __launch_bounds__(256) void conv_w(const float* __restrict__ W,
                                              u16* __restrict__ Wb) {
  int i = blockIdx.x * 256 + threadIdx.x;     // over 4M/4 = 1M float4
  float4 w = ((const float4*)W)[i];
  u16x4 o = { f2bf(w.x), f2bf(w.y), f2bf(w.z), f2bf(w.w) };
  ((u16x4*)Wb)[i] = o;
}

// ---------------- h0[b][j] = tanh(Txh[x[b,0]][j])  (no b_hh at step 0) ----------------
__global__ __launch_bounds__(256) void init_h0(const float* __restrict__ Txh,
                                               const int* __restrict__ x,
                                               u16* __restrict__ H0) {
  int idx = blockIdx.x * 256 + threadIdx.x;   // 1024*2048 = 2M
  int b = idx >> 11, j = idx & 2047;
  int xv = x[b * S_];
  H0[idx] = f2bf(fast_tanh(Txh[xv * H_ + j]));
}

// ---------------- one recurrence step ----------------
// C[1024x2048] = Hin * W^T. 256 WGs (1/CU), 512 threads = 8 waves.
// WG tile 128m x 64n; waves = (wm 0..1) x (wk 0..3); wave tile 64x64 over K=512
// (K-split x4 inside the WG, combined through LDS at the end).
// Per round r (16 rounds): DMA-stage the 32-k slice of all 4 K-quarters in
// FRAG-MAJOR layout (per-lane global src, lane-linear LDS dst) -> frag reads are
// contiguous ds_read_b128 (m97-proven, conflict-free). Double-buffered (96 KB),
// combine buffer (128 KB) overlaps staging buffers via union.
// XCD swizzle: per-XCD footprint A 2 MB + W 2 MB (L2/L3-friendly).
__global__ __launch_bounds__(512, 2) void rnn_step(const u16* __restrict__ Hin,
                                                   const u16* __restrict__ Wb,
                                                   const float* __restrict__ Txh,
                                                   const int* __restrict__ x,
                                                   const float* __restrict__ b_hh,
                                                   u16* __restrict__ Hout,
                                                   int t) {
  __shared__ union ShMem {
    struct {
      __align__(16) u16 A[2][4][4096];    // [buf][q][512 slots x 8 u16] = 64 KB
      __align__(16) u16 Bq[2][4][2048];   // [buf][q][256 slots x 8 u16] = 32 KB
    } st;
    __align__(16) float C[8][4096];       // [w = wm*4+wk][64x64 f32] = 128 KB
  } sh;

  const int tid = threadIdx.x;
  const int bid = blockIdx.x;
  const int xcd = bid & 7, sl = bid >> 3;
  const int bm = ((xcd >> 2) * 4 + (sl >> 3)) * 128;   // 8 m-groups of 128
  const int bn = ((xcd & 3) * 8 + (sl & 7)) * 64;      // 32 n-groups of 64

  const int w = tid >> 6, l = tid & 63;
  const int wm = w >> 2, wk = w & 3;
  const int lane16 = l & 15, quad = l >> 4;

  // staging decode: s_wm = tid>>8 (0..1), s_b = (tid>>6)&3 (block), lane = tid&63
  const int s_wm = tid >> 8;
  const int s_b  = (tid >> 6) & 3;
  const int a_row = bm + s_wm * 64 + s_b * 16 + lane16;
  const int b_row = bn + s_b * 16 + lane16;
  const u16* aHin = Hin + (size_t)a_row * H_ + quad * 8;
  const u16* bWb  = Wb  + (size_t)b_row * H_ + quad * 8;

  // per round: 6 gl2lds/thread -> A: quarter i slice; B: quarters (0,1)+s_wm*... 
#define STAGE(r, buf)                                                         \
  {                                                                           \
    _Pragma("unroll")                                                         \
    for (int i = 0; i < 4; ++i)                                               \
      gl2lds16(aHin + (size_t)i * 512 + (r) * 32,                             \
               &sh.st.A[buf][i][(s_wm * 4 + s_b) * 512]);                     \
    _Pragma("unroll")                                                         \
    for (int i = 0; i < 2; ++i) {                                             \
      int q = i * 2 + s_wm;                                                   \
      gl2lds16(bWb + (size_t)q * 512 + (r) * 32,                              \
               &sh.st.Bq[buf][q][s_b * 512]);                                 \
    }                                                                         \
  }

  v4f acc[4][4];
#pragma unroll
  for (int i = 0; i < 4; ++i)
#pragma unroll
    for (int j = 0; j < 4; ++j) acc[i][j] = (v4f){0.f, 0.f, 0.f, 0.f};

  STAGE(0, 0);
  __syncthreads();

  for (int r = 0; r < 16; ++r) {
    const int cur = r & 1;
    if (r < 15) STAGE(r + 1, cur ^ 1);

    v8s a[4], bq[4];
#pragma unroll
    for (int i = 0; i < 4; ++i)
      a[i] = *(const v8s*)&sh.st.A[cur][wk][(wm * 4 + i) * 512 + l * 8];
#pragma unroll
    for (int j = 0; j < 4; ++j)
      bq[j] = *(const v8s*)&sh.st.Bq[cur][wk][j * 512 + l * 8];
#pragma unroll
    for (int i = 0; i < 4; ++i)
#pragma unroll
      for (int j = 0; j < 4; ++j)
        acc[i][j] = __builtin_amdgcn_mfma_f32_16x16x32_bf16(a[i], bq[j], acc[i][j], 0, 0, 0);

    __syncthreads();   // next buffer's DMA drained; cur free for restage
  }

  // ---- write partials to combine buffer (overlaps staging LDS; barrier above) ----
  // C/D layout: col=lane&15, row=quad*4+reg  [m89-verified]
  {
    float* cw = sh.C[w];
#pragma unroll
    for (int i = 0; i < 4; ++i)
#pragma unroll
      for (int j = 0; j < 4; ++j)
#pragma unroll
        for (int rr = 0; rr < 4; ++rr)
          cw[(i * 16 + quad * 4 + rr) * 64 + j * 16 + lane16] = acc[i][j][rr];
  }
  __syncthreads();

  // ---- distributed combine + epilogue: wave w owns rows [w*16, +16) of the 128 ----
  {
    const int re = w * 16 + (l >> 2);    // 0..127 row within WG tile
    const int wmE = re >> 6;
    const int rlE = re & 63;
    const int colb = (l & 3) * 16;       // 16-col block within 64
    v4f s4[4];
#pragma unroll
    for (int c = 0; c < 4; ++c)
      s4[c] = *(const v4f*)&sh.C[wmE * 4 + 0][rlE * 64 + colb + c * 4];
#pragma unroll
    for (int p = 1; p < 4; ++p)
#pragma unroll
      for (int c = 0; c < 4; ++c)
        s4[c] += *(const v4f*)&sh.C[wmE * 4 + p][rlE * 64 + colb + c * 4];

    const int row = bm + re;
    const int xv = x[row * S_ + t];
    const float* trow = Txh + (size_t)xv * H_ + bn + colb;
    const float* bh = b_hh + bn + colb;
    u16 ob[16];
#pragma unroll
    for (int c = 0; c < 4; ++c) {
      float4 tt = *(const float4*)(trow + c * 4);
      float4 bb = *(const float4*)(bh + c * 4);
      ob[c * 4 + 0] = f2bf(fast_tanh(s4[c][0] + tt.x + bb.x));
      ob[c * 4 + 1] = f2bf(fast_tanh(s4[c][1] + tt.y + bb.y));
      ob[c * 4 + 2] = f2bf(fast_tanh(s4[c][2] + tt.z + bb.z));
      ob[c * 4 + 3] = f2bf(fast_tanh(s4[c][3] + tt.w + bb.w));
    }
    u16* orow = Hout + (size_t)row * H_ + bn + colb;
    u16x8 o0 = { ob[0], ob[1], ob[2], ob[3], ob[4], ob[5], ob[6], ob[7] };
    u16x8 o1 = { ob[8], ob[9], ob[10], ob[11], ob[12], ob[13], ob[14], ob[15] };
    ((u16x8*)orow)[0] = o0;
    ((u16x8*)orow)[1] = o1;
  }
#undef STAGE
}

// ---------------- o = hT @ W_oh^T + b_oh ; softmax over 10 ----------------
__global__ __launch_bounds__(256) void out_softmax(const u16* __restrict__ Hf,
                                                   const float* __restrict__ W_oh,
                                                   const float* __restrict__ b_oh,
                                                   float* __restrict__ out) {
  int b = blockIdx.x, tid = threadIdx.x;
  float hv[8];
  const u16* hr = Hf + (size_t)b * H_ + tid * 8;
#pragma unroll
  for (int u = 0; u < 8; ++u) hv[u] = bf2f(hr[u]);
  float acc[O_];
#pragma unroll
  for (int i = 0; i < O_; ++i) {
    const float* wr = W_oh + (size_t)i * H_ + tid * 8;
    float s = 0.f;
#pragma unroll
    for (int u = 0; u < 8; ++u) s = fmaf(hv[u], wr[u], s);
    acc[i] = s;
  }
#pragma unroll
  for (int off = 32; off > 0; off >>= 1)
#pragma unroll
    for (int i = 0; i < O_; ++i) acc[i] += __shfl_down(acc[i], off);
  __shared__ float red[4][O_];
  if ((tid & 63) == 0)
#pragma unroll
    for (int i = 0; i < O_; ++i) red[tid >> 6][i] = acc[i];
  __syncthreads();
  if (tid == 0) {
    float o[O_], mx = -1e30f;
#pragma unroll
    for (int i = 0; i < O_; ++i) {
      o[i] = red[0][i] + red[1][i] + red[2][i] + red[3][i] + b_oh[i];
      mx = fmaxf(mx, o[i]);
    }
    float se = 0.f;
#pragma unroll
    for (int i = 0; i < O_; ++i) { o[i] = __expf(o[i] - mx); se += o[i]; }
    float inv = 1.f / se;
#pragma unroll
    for (int i = 0; i < O_; ++i) out[b * O_ + i] = o[i] * inv;
  }
}

extern "C" void kernel_launch(void* const* d_in, const int* in_sizes, int n_in,
                              void* d_out, int out_size, void* d_ws, size_t ws_size,
                              hipStream_t stream) {
  const int*   x     = (const int*)  d_in[0];
  const float* embed = (const float*)d_in[1];
  const float* W_hx  = (const float*)d_in[2];
  const float* b_hx  = (const float*)d_in[3];
  const float* W_hh  = (const float*)d_in[4];
  const float* b_hh  = (const float*)d_in[5];
  const float* W_oh  = (const float*)d_in[6];
  const float* b_oh  = (const float*)d_in[7];
  float* out = (float*)d_out;

  // workspace: Txh 80KB | Wb 8MB | Ha 4MB | Hb 4MB  (~16.1 MB)
  char* ws = (char*)d_ws;
  float* Txh = (float*)ws;
  u16* Wb    = (u16*)(ws + (80 << 10));
  u16* Ha    = (u16*)(ws + (80 << 10) + (8 << 20));
  u16* Hb    = (u16*)(ws + (80 << 10) + (12 << 20));

  make_table<<<80, 256, 0, stream>>>(embed, W_hx, b_hx, Txh);
  conv_w<<<4096, 256, 0, stream>>>(W_hh, Wb);
  init_h0<<<8192, 256, 0, stream>>>(Txh, x, Ha);

  for (int t = 1; t < S_; ++t) {
    const u16* hin = (t & 1) ? Ha : Hb;
    u16* hout = (t & 1) ? Hb : Ha;
    rnn_step<<<256, 512, 0, stream>>>(hin, Wb, Txh, x, b_hh, hout, t);
  }
  // t=127 (odd) wrote Hb
  out_softmax<<<B_, 256, 0, stream>>>(Hb, W_oh, b_oh, out);
}